// Round 4
// baseline (39.909 us; speedup 1.0000x reference)
//
#include <hip/hip_runtime.h>

#define BS 64
#define NQ 300
#define NTGT 1024
#define TT 16
#define MCOL 300
#define NROW 16
#define STR 304
#define BIGF 1000000000.0f
#define BIG2 2000000000.0f
#define BIG4 4000000000.0f

// ---- shared per-cell cost (identical formula in both paths) ----
__device__ __forceinline__ float cell_cost(float p0, float pcx, float pcy, float pw, float ph,
                                           float px1, float py1, float px2, float py2, float parea,
                                           float4 tb)
{
    float cb = fabsf(pcx - tb.x) + fabsf(pcy - tb.y) + fabsf(pw - tb.z) + fabsf(ph - tb.w);
    float tx1 = tb.x - 0.5f*tb.z, ty1 = tb.y - 0.5f*tb.w;
    float tx2 = tb.x + 0.5f*tb.z, ty2 = tb.y + 0.5f*tb.w;
    float tarea = (tx2 - tx1) * (ty2 - ty1);
    float ltx = fmaxf(px1, tx1), lty = fmaxf(py1, ty1);
    float rbx = fminf(px2, tx2), rby = fminf(py2, ty2);
    float iw = fmaxf(rbx - ltx, 0.f), ih = fmaxf(rby - lty, 0.f);
    float inter = iw * ih;
    float uni = parea + tarea - inter;
    float iou = inter * __builtin_amdgcn_rcpf(uni);
    float ex1 = fminf(px1, tx1), ey1 = fminf(py1, ty1);
    float ex2 = fmaxf(px2, tx2), ey2 = fmaxf(py2, ty2);
    float areae = (ex2 - ex1) * (ey2 - ey1);
    float giou = iou - (areae - uni) * __builtin_amdgcn_rcpf(areae);
    return cb - giou - p0;
}

// ---- DPP wave-64 min reductions (result valid in lane 63) ----
template<int CTRL>
__device__ __forceinline__ float dppmin_f(float x) {
    int t = __builtin_amdgcn_update_dpp(__float_as_int(BIGF), __float_as_int(x),
                                        CTRL, 0xF, 0xF, false);
    return fminf(x, __int_as_float(t));
}
template<int CTRL>
__device__ __forceinline__ int dppmin_i(int x) {
    int t = __builtin_amdgcn_update_dpp(0x7FFFFFFF, x, CTRL, 0xF, 0xF, false);
    return (t < x) ? t : x;
}
__device__ __forceinline__ float wave_min_f(float x) {
    x = dppmin_f<0x111>(x);  // row_shr:1
    x = dppmin_f<0x112>(x);  // row_shr:2
    x = dppmin_f<0x114>(x);  // row_shr:4
    x = dppmin_f<0x118>(x);  // row_shr:8
    x = dppmin_f<0x142>(x);  // row_bcast:15
    x = dppmin_f<0x143>(x);  // row_bcast:31
    return x;
}
__device__ __forceinline__ int wave_min_i(int x) {
    x = dppmin_i<0x111>(x);
    x = dppmin_i<0x112>(x);
    x = dppmin_i<0x114>(x);
    x = dppmin_i<0x118>(x);
    x = dppmin_i<0x142>(x);
    x = dppmin_i<0x143>(x);
    return x;
}

// static-index select chain over 5 regs (k0 wave-uniform)
__device__ __forceinline__ int sel5i(const int a[5], int k0) {
    int r = a[0];
    r = (k0 == 1) ? a[1] : r;
    r = (k0 == 2) ? a[2] : r;
    r = (k0 == 3) ? a[3] : r;
    r = (k0 == 4) ? a[4] : r;
    return r;
}
__device__ __forceinline__ float sel5f(const float a[5], int k0) {
    float r = a[0];
    r = (k0 == 1) ? a[1] : r;
    r = (k0 == 2) ? a[2] : r;
    r = (k0 == 3) ? a[3] : r;
    r = (k0 == 4) ? a[4] : r;
    return r;
}

__global__ __launch_bounds__(256) void fused_kernel(
    const float* __restrict__ logits,
    const float* __restrict__ boxes,
    const float* __restrict__ tgt,
    float* __restrict__ out)
{
    __shared__ float ca[16 * STR + 32];
    const int tid = threadIdx.x;

    if (blockIdx.x >= BS) {
        // ================= cost-matrix path: one q per block, 4 t per thread ==========
        int q = blockIdx.x - BS;                     // 0..19199, uniform per block
        float l0v = logits[2*q], l1v = logits[2*q + 1];
        float p0 = __builtin_amdgcn_rcpf(1.f + __expf(l1v - l0v));   // softmax[0]
        float4 pb = ((const float4*)boxes)[q];
        float px1 = pb.x - 0.5f*pb.z, py1 = pb.y - 0.5f*pb.w;
        float px2 = pb.x + 0.5f*pb.z, py2 = pb.y + 0.5f*pb.w;
        float parea = (px2 - px1) * (py2 - py1);

        int t0 = tid << 2;
        const float4* tgt4 = (const float4*)tgt;
        float4 tb0 = tgt4[t0+0], tb1 = tgt4[t0+1], tb2 = tgt4[t0+2], tb3 = tgt4[t0+3];
        float4 r;
        r.x = cell_cost(p0, pb.x, pb.y, pb.z, pb.w, px1, py1, px2, py2, parea, tb0);
        r.y = cell_cost(p0, pb.x, pb.y, pb.z, pb.w, px1, py1, px2, py2, parea, tb1);
        r.z = cell_cost(p0, pb.x, pb.y, pb.z, pb.w, px1, py1, px2, py2, parea, tb2);
        r.w = cell_cost(p0, pb.x, pb.y, pb.z, pb.w, px1, py1, px2, py2, parea, tb3);
        *(float4*)(out + (size_t)q * NTGT + t0) = r;
        return;
    }

    // ================= hungarian path: block b handles batch b =======================
    const int b = blockIdx.x;

    {
        auto fill_row = [&](int q) {
            float l0v = logits[(b*NQ + q)*2 + 0], l1v = logits[(b*NQ + q)*2 + 1];
            float p0 = __builtin_amdgcn_rcpf(1.f + __expf(l1v - l0v));
            float4 pb = ((const float4*)boxes)[b*NQ + q];
            float px1 = pb.x - 0.5f*pb.z, py1 = pb.y - 0.5f*pb.w;
            float px2 = pb.x + 0.5f*pb.z, py2 = pb.y + 0.5f*pb.w;
            float parea = (px2 - px1) * (py2 - py1);
            #pragma unroll
            for (int t = 0; t < TT; ++t) {
                float4 tb = ((const float4*)tgt)[b*TT + t];
                ca[t*STR + 1 + q] =
                    cell_cost(p0, pb.x, pb.y, pb.z, pb.w, px1, py1, px2, py2, parea, tb);
            }
        };
        fill_row(tid);                      // q = 0..255
        if (tid >= 212) fill_row(tid + 44); // q = 256..299
        if (tid < 16) ca[tid*STR] = 0.f;    // dummy col 0
    }
    __syncthreads();
    if (tid >= 64) return;                  // wave 0 runs JV, barrier-free

    __builtin_amdgcn_s_setprio(1);

    const int lane = tid;

    // ---- load this lane's 5 columns of all 16 rows into registers ----
    // inactive cols (j>300) get BIG4 so they can never win any min.
    float R[16][5];
    #pragma unroll
    for (int t = 0; t < 16; ++t) {
        #pragma unroll
        for (int k = 0; k < 4; ++k)
            R[t][k] = ca[t*STR + lane + (k << 6)];
        R[t][4] = (lane <= 44) ? ca[t*STR + lane + 256] : BIG4;
    }

    // ---- register-only JV shortest-augmenting-path ----
    int   p_reg[5]   = {0,0,0,0,0};
    int   way_reg[5] = {0,0,0,0,0};
    float vloc[5]    = {0.f,0.f,0.f,0.f,0.f};   // persistent v (clean)
    float w[5], minv[5], ur_reg[5];             // w = v shadow with used-penalty
    float u_lane = 0.f;

    for (int i = 1; i <= NROW; ++i) {
        if (lane == 0) p_reg[0] = i;
        unsigned usedm = 0, treemask = 0;
        #pragma unroll
        for (int k = 0; k < 5; ++k) { minv[k] = BIGF; way_reg[k] = 0; w[k] = vloc[k]; }
        #pragma unroll
        for (int k = 0; k < 5; ++k) ur_reg[k] = __shfl(u_lane, p_reg[k], 64); // u[p[j]]

        int j0 = 0;
        for (;;) {
            int l0 = j0 & 63, k0 = j0 >> 6;                   // uniform
            int i0 = __builtin_amdgcn_readlane(sel5i(p_reg, k0), l0);
            if (i0 == 0) break;
            float ui0 = __int_as_float(
                __builtin_amdgcn_readlane(__float_as_int(sel5f(ur_reg, k0)), l0));
            // mark j0 used: penalize its cu by +2e9, freeze its minv at BIGF
            #pragma unroll
            for (int k = 0; k < 5; ++k)
                if (k == k0 && lane == l0) { usedm |= (1u << k); w[k] -= BIG2; minv[k] = BIGF; }
            treemask |= (1u << i0);                            // uniform

            // row select: uniform jump table, 5 register moves
            float c0, c1, c2, c3, c4;
            switch (i0) {
#define ROWCASE(T) case (T)+1: c0=R[T][0]; c1=R[T][1]; c2=R[T][2]; c3=R[T][3]; c4=R[T][4]; break;
                ROWCASE(0)  ROWCASE(1)  ROWCASE(2)  ROWCASE(3)
                ROWCASE(4)  ROWCASE(5)  ROWCASE(6)  ROWCASE(7)
                ROWCASE(8)  ROWCASE(9)  ROWCASE(10) ROWCASE(11)
                ROWCASE(12) ROWCASE(13) ROWCASE(14) ROWCASE(15)
#undef ROWCASE
                default: __builtin_unreachable();
            }

            // mask-free scan: used cols have cu ~ +2e9, inactive ~ +4e9
            float cu[5];
            cu[0] = c0 - ui0 - w[0];
            cu[1] = c1 - ui0 - w[1];
            cu[2] = c2 - ui0 - w[2];
            cu[3] = c3 - ui0 - w[3];
            cu[4] = c4 - ui0 - w[4];
            #pragma unroll
            for (int k = 0; k < 5; ++k) {
                bool lt = cu[k] < minv[k];
                way_reg[k] = lt ? j0 : way_reg[k];
                minv[k] = lt ? cu[k] : minv[k];
            }
            // 5 -> 1 lex tree (tie -> smaller j; j ascending in k)
            float v01 = fminf(minv[0], minv[1]); int j01 = (minv[0] <= minv[1]) ? lane : lane + 64;
            float v23 = fminf(minv[2], minv[3]); int j23 = (minv[2] <= minv[3]) ? lane + 128 : lane + 192;
            float v03 = fminf(v01, v23);         int j03 = (v01 <= v23) ? j01 : j23;
            float bv  = fminf(v03, minv[4]);     int bj  = (v03 <= minv[4]) ? j03 : lane + 256;

            // wave argmin: plain DPP value chain + single-lane ballot fast path
            float mv = wave_min_f(bv);
            float delta = __int_as_float(__builtin_amdgcn_readlane(__float_as_int(mv), 63));
            unsigned long long eq = __ballot(bv == delta);
            int j1;
            if (__popcll(eq) == 1) {
                j1 = __builtin_amdgcn_readlane(bj, (int)(__ffsll((unsigned long long)eq) - 1));
            } else {  // exact-tie fallback: smallest j among tied lanes (matches jnp.argmin)
                int cand = (bv == delta) ? bj : 0x7FFFFFFF;
                j1 = __builtin_amdgcn_readlane(wave_min_i(cand), 63);
            }

            #pragma unroll
            for (int k = 0; k < 5; ++k) {
                bool us = ((usedm >> k) & 1u) != 0u;
                vloc[k]   = us ? vloc[k] - delta   : vloc[k];
                w[k]      = us ? w[k] - delta      : w[k];
                ur_reg[k] = us ? ur_reg[k] + delta : ur_reg[k];
                minv[k]   = us ? minv[k]           : minv[k] - delta;
            }
            if (lane <= NROW && ((treemask >> lane) & 1u)) u_lane += delta;
            j0 = j1;
        }
        // augment: p[j0] = p[way[j0]] walking back to col 0 (uniform readlanes)
        while (j0 != 0) {
            int l0 = j0 & 63, k0 = j0 >> 6;
            int jn = __builtin_amdgcn_readlane(sel5i(way_reg, k0), l0);
            int pn = __builtin_amdgcn_readlane(sel5i(p_reg, jn >> 6), jn & 63);
            #pragma unroll
            for (int k = 0; k < 5; ++k)
                if (k == k0 && lane == l0) p_reg[k] = pn;
            j0 = jn;
        }
    }

    __builtin_amdgcn_s_setprio(0);

    // ---- extraction: row_ind/col_ind in ascending query order ----
    const size_t ROWB = (size_t)BS * NQ * NTGT;
    const size_t COLB = ROWB + (size_t)BS * TT;
    int base = 0;
    #pragma unroll
    for (int k = 0; k < 5; ++k) {
        int pk1 = (k < 4) ? __shfl(p_reg[k + 1], 0, 64) : 0;   // p[64(k+1)]
        int psh = __shfl(p_reg[k], (lane + 1) & 63, 64);       // p[64k + lane+1]
        int q = (k << 6) | lane;
        int a = (lane == 63) ? pk1 : psh;                      // = p[q+1]
        if (q >= MCOL) a = 0;
        unsigned long long mb = __ballot(a > 0);
        int pos = base + __popcll(mb & ((1ull << lane) - 1ull));
        if (a > 0) {
            out[ROWB + (size_t)b * TT + pos] = (float)q;
            out[COLB + (size_t)b * TT + pos] = (float)(a - 1);
        }
        base += __popcll(mb);
    }
}

extern "C" void kernel_launch(void* const* d_in, const int* in_sizes, int n_in,
                              void* d_out, int out_size, void* d_ws, size_t ws_size,
                              hipStream_t stream) {
    const float* logits = (const float*)d_in[0];   // (64,300,2)
    const float* boxes  = (const float*)d_in[1];   // (64,300,4)
    const float* tgt    = (const float*)d_in[2];   // (1024,4)
    float* out = (float*)d_out;

    // blocks 0..63: hungarian (self-contained); blocks 64..19263: cost matrix (1 q each)
    fused_kernel<<<dim3(BS + BS*NQ), 256, 0, stream>>>(logits, boxes, tgt, out);
}

// Round 5
// 34.368 us; speedup vs baseline: 1.1612x; 1.1612x over previous
//
#include <hip/hip_runtime.h>

#define BS 64
#define NQ 300
#define NTGT 1024
#define TT 16
#define MCOL 300
#define NROW 16
#define STR 304
#define BIGF 1000000000.0f
#define BIG2 2000000000.0f
#define BIG4 4000000000.0f

// ---- shared per-cell cost (identical formula in both paths) ----
__device__ __forceinline__ float cell_cost(float p0, float pcx, float pcy, float pw, float ph,
                                           float px1, float py1, float px2, float py2, float parea,
                                           float4 tb)
{
    float cb = fabsf(pcx - tb.x) + fabsf(pcy - tb.y) + fabsf(pw - tb.z) + fabsf(ph - tb.w);
    float tx1 = tb.x - 0.5f*tb.z, ty1 = tb.y - 0.5f*tb.w;
    float tx2 = tb.x + 0.5f*tb.z, ty2 = tb.y + 0.5f*tb.w;
    float tarea = (tx2 - tx1) * (ty2 - ty1);
    float ltx = fmaxf(px1, tx1), lty = fmaxf(py1, ty1);
    float rbx = fminf(px2, tx2), rby = fminf(py2, ty2);
    float iw = fmaxf(rbx - ltx, 0.f), ih = fmaxf(rby - lty, 0.f);
    float inter = iw * ih;
    float uni = parea + tarea - inter;
    float iou = inter * __builtin_amdgcn_rcpf(uni);
    float ex1 = fminf(px1, tx1), ey1 = fminf(py1, ty1);
    float ex2 = fmaxf(px2, tx2), ey2 = fmaxf(py2, ty2);
    float areae = (ex2 - ex1) * (ey2 - ey1);
    float giou = iou - (areae - uni) * __builtin_amdgcn_rcpf(areae);
    return cb - giou - p0;
}

// ---- DPP wave-64 min reductions (result valid in lane 63) ----
template<int CTRL>
__device__ __forceinline__ float dppmin_f(float x) {
    int t = __builtin_amdgcn_update_dpp(__float_as_int(BIGF), __float_as_int(x),
                                        CTRL, 0xF, 0xF, false);
    return fminf(x, __int_as_float(t));
}
template<int CTRL>
__device__ __forceinline__ int dppmin_i(int x) {
    int t = __builtin_amdgcn_update_dpp(0x7FFFFFFF, x, CTRL, 0xF, 0xF, false);
    return (t < x) ? t : x;
}
__device__ __forceinline__ float wave_min_f(float x) {
    x = dppmin_f<0x111>(x);  // row_shr:1
    x = dppmin_f<0x112>(x);  // row_shr:2
    x = dppmin_f<0x114>(x);  // row_shr:4
    x = dppmin_f<0x118>(x);  // row_shr:8
    x = dppmin_f<0x142>(x);  // row_bcast:15
    x = dppmin_f<0x143>(x);  // row_bcast:31
    return x;
}
__device__ __forceinline__ int wave_min_i(int x) {
    x = dppmin_i<0x111>(x);
    x = dppmin_i<0x112>(x);
    x = dppmin_i<0x114>(x);
    x = dppmin_i<0x118>(x);
    x = dppmin_i<0x142>(x);
    x = dppmin_i<0x143>(x);
    return x;
}

// static-index select chain over 5 regs (k0 wave-uniform)
__device__ __forceinline__ int sel5i(const int a[5], int k0) {
    int r = a[0];
    r = (k0 == 1) ? a[1] : r;
    r = (k0 == 2) ? a[2] : r;
    r = (k0 == 3) ? a[3] : r;
    r = (k0 == 4) ? a[4] : r;
    return r;
}

__global__ __launch_bounds__(256) void fused_kernel(
    const float* __restrict__ logits,
    const float* __restrict__ boxes,
    const float* __restrict__ tgt,
    float* __restrict__ out)
{
    __shared__ float ca[16 * STR + 32];
    const int tid = threadIdx.x;

    if (blockIdx.x >= BS) {
        // ================= cost-matrix path: one q per block, 4 t per thread ==========
        int q = blockIdx.x - BS;                     // 0..19199, uniform per block
        float l0v = logits[2*q], l1v = logits[2*q + 1];
        float p0 = __builtin_amdgcn_rcpf(1.f + __expf(l1v - l0v));   // softmax[0]
        float4 pb = ((const float4*)boxes)[q];
        float px1 = pb.x - 0.5f*pb.z, py1 = pb.y - 0.5f*pb.w;
        float px2 = pb.x + 0.5f*pb.z, py2 = pb.y + 0.5f*pb.w;
        float parea = (px2 - px1) * (py2 - py1);

        int t0 = tid << 2;
        const float4* tgt4 = (const float4*)tgt;
        float4 tb0 = tgt4[t0+0], tb1 = tgt4[t0+1], tb2 = tgt4[t0+2], tb3 = tgt4[t0+3];
        float4 r;
        r.x = cell_cost(p0, pb.x, pb.y, pb.z, pb.w, px1, py1, px2, py2, parea, tb0);
        r.y = cell_cost(p0, pb.x, pb.y, pb.z, pb.w, px1, py1, px2, py2, parea, tb1);
        r.z = cell_cost(p0, pb.x, pb.y, pb.z, pb.w, px1, py1, px2, py2, parea, tb2);
        r.w = cell_cost(p0, pb.x, pb.y, pb.z, pb.w, px1, py1, px2, py2, parea, tb3);
        *(float4*)(out + (size_t)q * NTGT + t0) = r;
        return;
    }

    // ================= hungarian path: block b handles batch b =======================
    const int b = blockIdx.x;

    {
        auto fill_row = [&](int q) {
            float l0v = logits[(b*NQ + q)*2 + 0], l1v = logits[(b*NQ + q)*2 + 1];
            float p0 = __builtin_amdgcn_rcpf(1.f + __expf(l1v - l0v));
            float4 pb = ((const float4*)boxes)[b*NQ + q];
            float px1 = pb.x - 0.5f*pb.z, py1 = pb.y - 0.5f*pb.w;
            float px2 = pb.x + 0.5f*pb.z, py2 = pb.y + 0.5f*pb.w;
            float parea = (px2 - px1) * (py2 - py1);
            #pragma unroll
            for (int t = 0; t < TT; ++t) {
                float4 tb = ((const float4*)tgt)[b*TT + t];
                ca[t*STR + 1 + q] =
                    cell_cost(p0, pb.x, pb.y, pb.z, pb.w, px1, py1, px2, py2, parea, tb);
            }
        };
        fill_row(tid);                      // q = 0..255
        if (tid >= 212) fill_row(tid + 44); // q = 256..299
        if (tid < 16) ca[tid*STR] = 0.f;    // dummy col 0
    }
    __syncthreads();
    if (tid >= 64) return;                  // wave 0 runs JV, barrier-free

    __builtin_amdgcn_s_setprio(1);

    const int lane = tid;
    const bool act4 = (lane <= 44);         // col j = lane+256 valid only if j<=300

    // ---- register-only JV shortest-augmenting-path ----
    // lane owns cols j = lane + 64k, k=0..4. u[row] lives in lane 'row' of u_lane.
    // 'used' column encoding: w[k] < -1e9 (w = v shadow with -2e9 penalty).
    int   p_reg[5]   = {0,0,0,0,0};
    int   way_reg[5] = {0,0,0,0,0};
    float vloc[5]    = {0.f,0.f,0.f,0.f,0.f};   // persistent clean dual v
    float w[5], minv[5];
    float u_lane = 0.f;

    for (int i = 1; i <= NROW; ++i) {
        if (lane == 0) p_reg[0] = i;
        unsigned treemask = 0;
        #pragma unroll
        for (int k = 0; k < 5; ++k) { minv[k] = BIGF; way_reg[k] = 0; w[k] = vloc[k]; }
        if (lane == 0) w[0] -= BIG2;        // virtual col 0 is used from the start

        int i0 = i, j0 = 0;
        {   // initial row read (row i)
            const float* rb = &ca[(i0 - 1) * STR + lane];
            float c4 = rb[256];
            minv[4] = BIGF;                 // (keep compiler from reordering oddly)
            float c0 = rb[0], c1 = rb[64], c2 = rb[128], c3 = rb[192];
            w[4] = act4 ? w[4] : w[4];      // no-op
            // guard inactive lanes: their rb[256] aliases next row's data
            curinit:;
            // assign
            // (plain block below)
            (void)0;
            // fallthrough
            // ---
            // store into loop-carried regs
            // (declared below)
            // NOTE: declarations after label not allowed; restructure:
            goto after_init_decl;
            after_init_decl:;
            // real init done after declarations below
            // (see cur0..cur4 initialization)
            // -- this block intentionally minimal --
            (void)c0; (void)c1; (void)c2; (void)c3; (void)c4;
        }
        const float* rb0 = &ca[(i0 - 1) * STR + lane];
        float cur0 = rb0[0], cur1 = rb0[64], cur2 = rb0[128], cur3 = rb0[192];
        float cur4 = act4 ? rb0[256] : BIG4;

        for (;;) {
            float ui0 = __int_as_float(
                __builtin_amdgcn_readlane(__float_as_int(u_lane), i0));
            treemask |= (1u << i0);                       // uniform

            // scan: used cols have cu ~ +2e9 (w penalty), inactive ~ +4e9
            float cu0 = cur0 - ui0 - w[0];
            float cu1 = cur1 - ui0 - w[1];
            float cu2 = cur2 - ui0 - w[2];
            float cu3 = cur3 - ui0 - w[3];
            float cu4 = cur4 - ui0 - w[4];
            {
                bool lt;
                lt = cu0 < minv[0]; way_reg[0] = lt ? j0 : way_reg[0]; minv[0] = lt ? cu0 : minv[0];
                lt = cu1 < minv[1]; way_reg[1] = lt ? j0 : way_reg[1]; minv[1] = lt ? cu1 : minv[1];
                lt = cu2 < minv[2]; way_reg[2] = lt ? j0 : way_reg[2]; minv[2] = lt ? cu2 : minv[2];
                lt = cu3 < minv[3]; way_reg[3] = lt ? j0 : way_reg[3]; minv[3] = lt ? cu3 : minv[3];
                lt = cu4 < minv[4]; way_reg[4] = lt ? j0 : way_reg[4]; minv[4] = lt ? cu4 : minv[4];
            }
            // 5 -> 1 lex tree (tie -> smaller j; j ascending in k)
            float v01 = fminf(minv[0], minv[1]); int j01 = (minv[0] <= minv[1]) ? lane : lane + 64;
            float v23 = fminf(minv[2], minv[3]); int j23 = (minv[2] <= minv[3]) ? lane + 128 : lane + 192;
            float v03 = fminf(v01, v23);         int j03 = (v01 <= v23) ? j01 : j23;
            float bv  = fminf(v03, minv[4]);     int bj  = (v03 <= minv[4]) ? j03 : lane + 256;

            // wave argmin: DPP value chain + single-winner ballot fast path
            float mv = wave_min_f(bv);
            float delta = __int_as_float(__builtin_amdgcn_readlane(__float_as_int(mv), 63));
            unsigned long long eq = __ballot(bv == delta);
            int j1;
            if (__popcll(eq) == 1) {
                j1 = __builtin_amdgcn_readlane(bj, (int)(__ffsll(eq) - 1));
            } else {  // exact-tie fallback: smallest j among tied lanes (matches jnp.argmin)
                int cand = (bv == delta) ? bj : 0x7FFFFFFF;
                j1 = __builtin_amdgcn_readlane(wave_min_i(cand), 63);
            }
            int i0n = __builtin_amdgcn_readlane(sel5i(p_reg, j1 >> 6), j1 & 63);

            // prefetch next row NOW — updates below hide the LDS latency
            if (i0n != 0) {
                const float* rn = &ca[(i0n - 1) * STR + lane];
                cur0 = rn[0]; cur1 = rn[64]; cur2 = rn[128]; cur3 = rn[192];
                cur4 = act4 ? rn[256] : BIG4;
            }

            // dual updates for this delta (overlapped with prefetch latency)
            if (lane <= NROW && ((treemask >> lane) & 1u)) u_lane += delta;
            #pragma unroll
            for (int k = 0; k < 5; ++k) {
                float du = (w[k] < -BIGF) ? delta : 0.f;   // used-col detection
                vloc[k] -= du;
                w[k]    -= du;
                minv[k] -= delta;    // frozen/used cols drift from 1e9 by <<1e6: harmless
            }
            // mark j1 used for the next iteration
            {
                int l1 = j1 & 63, k1 = j1 >> 6;
                #pragma unroll
                for (int k = 0; k < 5; ++k)
                    if (k == k1 && lane == l1) { w[k] -= BIG2; minv[k] = BIGF; }
            }
            j0 = j1; i0 = i0n;
            if (i0n == 0) break;
        }
        // augment: p[j0] = p[way[j0]] walking back to col 0 (uniform readlanes)
        while (j0 != 0) {
            int l0 = j0 & 63, k0 = j0 >> 6;
            int jn = __builtin_amdgcn_readlane(sel5i(way_reg, k0), l0);
            int pn = __builtin_amdgcn_readlane(sel5i(p_reg, jn >> 6), jn & 63);
            #pragma unroll
            for (int k = 0; k < 5; ++k)
                if (k == k0 && lane == l0) p_reg[k] = pn;
            j0 = jn;
        }
    }

    __builtin_amdgcn_s_setprio(0);

    // ---- extraction: row_ind/col_ind in ascending query order ----
    const size_t ROWB = (size_t)BS * NQ * NTGT;
    const size_t COLB = ROWB + (size_t)BS * TT;
    int base = 0;
    #pragma unroll
    for (int k = 0; k < 5; ++k) {
        int pk1 = (k < 4) ? __shfl(p_reg[k + 1], 0, 64) : 0;   // p[64(k+1)]
        int psh = __shfl(p_reg[k], (lane + 1) & 63, 64);       // p[64k + lane+1]
        int q = (k << 6) | lane;
        int a = (lane == 63) ? pk1 : psh;                      // = p[q+1]
        if (q >= MCOL) a = 0;
        unsigned long long mb = __ballot(a > 0);
        int pos = base + __popcll(mb & ((1ull << lane) - 1ull));
        if (a > 0) {
            out[ROWB + (size_t)b * TT + pos] = (float)q;
            out[COLB + (size_t)b * TT + pos] = (float)(a - 1);
        }
        base += __popcll(mb);
    }
}

extern "C" void kernel_launch(void* const* d_in, const int* in_sizes, int n_in,
                              void* d_out, int out_size, void* d_ws, size_t ws_size,
                              hipStream_t stream) {
    const float* logits = (const float*)d_in[0];   // (64,300,2)
    const float* boxes  = (const float*)d_in[1];   // (64,300,4)
    const float* tgt    = (const float*)d_in[2];   // (1024,4)
    float* out = (float*)d_out;

    // blocks 0..63: hungarian (self-contained); blocks 64..19263: cost matrix (1 q each)
    fused_kernel<<<dim3(BS + BS*NQ), 256, 0, stream>>>(logits, boxes, tgt, out);
}